// Round 3
// baseline (222.294 us; speedup 1.0000x reference)
//
#include <hip/hip_runtime.h>

// Problem constants: B=4, C=3, H=512, W=960, K2=16 -> K=4
#define BB 4
#define CC 3
#define HH 512
#define WW 960
#define HW (HH * WW)

// 2D tiling: 64x8 pixels per 256-thread block, 2 pixels per thread
#define TW 64
#define TH 8
#define NTX (WW / TW)          // 15
#define NTY (HH / TH)          // 64
#define NBLK (BB * NTX * NTY)  // 3840 (% 8 == 0 for XCD swizzle)

// Staged input tile: rows y0-5 .. y0+14 (20), cols x0-8 .. x0+71 (80), 3 ch.
// Row layout: [ch0 cols0..79][ch1][ch2][1 pad chunk] = 61 chunks = 244 floats.
// 244 mod 32 = 20 -> rows k apart hit distinct banks for k=1..7 (k=8 needs
// |dfy|~8 within a wave: negligible). Pad chunk is DMA'd from a duplicate
// source address (global_load_lds dest must stay linear) and never read.
#define ROWS 20
#define COLS 80
#define CH_STRIDE 80                     // floats between channels in a row
#define CHUNKS_PER_ROW 61                // 60 data + 1 pad
#define RSTRIDE (CHUNKS_PER_ROW * 4)     // 244 floats
#define DATA_FLOATS_PER_ROW (CC * COLS)  // 240
#define LDS_CHUNKS 1280                  // 5 full 256-lane DMA rounds (>= 20*61)
#define LDS_FLOATS (LDS_CHUNKS * 4)      // 5120 floats = 20480 B -> 8 blocks/CU

typedef __attribute__((address_space(1))) const unsigned int gu32;
typedef __attribute__((address_space(3))) unsigned int lu32;

__device__ __forceinline__ void compute_pixel(
    const float* __restrict__ lds, const float* __restrict__ ibase,
    int x, int y, int x0, int y0, float fx, float fy,
    const float* __restrict__ f, float* __restrict__ acc)
{
    acc[0] = 0.0f; acc[1] = 0.0f; acc[2] = 0.0f;

    const float x2 = (float)x + fx;
    const float y2 = (float)y + fy;
    const bool valid = (x2 >= 0.0f) && (x2 <= (float)(WW - 1)) &&
                       (y2 >= 0.0f) && (y2 <= (float)(HH - 1)) &&
                       (fabsf(fx) < (float)WW * 0.5f) &&
                       (fabsf(fy) < (float)HH * 0.5f);
    if (!valid) return;

    const int ix = (int)floorf(x2);
    const int iy = (int)floorf(y2);
    const float alpha = x2 - (float)ix;
    const float beta  = y2 - (float)iy;

    const float wTL = (1.0f - alpha) * (1.0f - beta);
    const float wTR = alpha * (1.0f - beta);
    const float wBL = (1.0f - alpha) * beta;
    const float wBR = alpha * beta;

    // Fold 16 taps x 4 bilinear weights into 5x5 (channel-independent).
    float Wm[5][5];
#pragma unroll
    for (int j = 0; j < 5; ++j)
#pragma unroll
        for (int i = 0; i < 5; ++i) Wm[j][i] = 0.0f;
#pragma unroll
    for (int dj = 0; dj < 4; ++dj) {
#pragma unroll
        for (int di = 0; di < 4; ++di) {
            const float fv = f[dj * 4 + di];
            Wm[dj][di]         += fv * wTL;
            Wm[dj][di + 1]     += fv * wTR;
            Wm[dj + 1][di]     += fv * wBL;
            Wm[dj + 1][di + 1] += fv * wBR;
        }
    }

    const int ixL0 = ix - 1;
    const int iyT0 = iy - 1;
    const int cs = ixL0 - (x0 - 8);   // col slot of window start
    const int rs = iyT0 - (y0 - 5);   // row slot of window start

    if ((unsigned)rs <= (unsigned)(ROWS - 5) &&
        (unsigned)cs <= (unsigned)(COLS - 5)) {
        // Fast path: b64 gather from LDS. Window aligned down to even col e0;
        // 3 float2 reads per row/channel; weight row barrel-shifted by cs&1.
        const int o  = cs & 1;
        const int e0 = cs - o;
        const float* lbase = lds + rs * RSTRIDE + e0;
#pragma unroll
        for (int j = 0; j < 5; ++j) {
            const float* lr = lbase + j * RSTRIDE;
            const float w0 = o ? 0.0f     : Wm[j][0];
            const float w1 = o ? Wm[j][0] : Wm[j][1];
            const float w2 = o ? Wm[j][1] : Wm[j][2];
            const float w3 = o ? Wm[j][2] : Wm[j][3];
            const float w4 = o ? Wm[j][3] : Wm[j][4];
            const float w5 = o ? Wm[j][4] : 0.0f;

            const float2 a0 = *(const float2*)(lr);
            const float2 a1 = *(const float2*)(lr + 2);
            const float2 a2 = *(const float2*)(lr + 4);
            acc[0] += a0.x * w0 + a0.y * w1 + a1.x * w2 +
                      a1.y * w3 + a2.x * w4 + a2.y * w5;

            const float2 b0 = *(const float2*)(lr + CH_STRIDE);
            const float2 b1 = *(const float2*)(lr + CH_STRIDE + 2);
            const float2 b2 = *(const float2*)(lr + CH_STRIDE + 4);
            acc[1] += b0.x * w0 + b0.y * w1 + b1.x * w2 +
                      b1.y * w3 + b2.x * w4 + b2.y * w5;

            const float2 c0 = *(const float2*)(lr + 2 * CH_STRIDE);
            const float2 c1 = *(const float2*)(lr + 2 * CH_STRIDE + 2);
            const float2 c2 = *(const float2*)(lr + 2 * CH_STRIDE + 4);
            acc[2] += c0.x * w0 + c0.y * w1 + c1.x * w2 +
                      c1.y * w3 + c2.x * w4 + c2.y * w5;
        }
    } else {
        // Rare fallback (|flow| beyond tile margin but still valid):
        // scalar clamped global gathers.
        int R[5], S[5];
#pragma unroll
        for (int j = 0; j < 5; ++j) R[j] = min(max(iyT0 + j, 0), HH - 1);
#pragma unroll
        for (int i = 0; i < 5; ++i) S[i] = min(max(ixL0 + i, 0), WW - 1);
#pragma unroll
        for (int j = 0; j < 5; ++j) {
            const float* r0 = ibase + (size_t)R[j] * WW;
#pragma unroll
            for (int i = 0; i < 5; ++i) {
                const float w = Wm[j][i];
                const size_t oidx = (size_t)S[i];
                acc[0] += r0[oidx] * w;
                acc[1] += r0[HW + oidx] * w;
                acc[2] += r0[2 * (size_t)HW + oidx] * w;
            }
        }
    }
}

__global__ __launch_bounds__(256)
void filter_interp_kernel(const float* __restrict__ inp,
                          const float* __restrict__ flow,
                          const float* __restrict__ filt,
                          float* __restrict__ out) {
    __shared__ float lds[LDS_FLOATS];

    // Bijective XCD-aware swizzle (NBLK % 8 == 0): ty-fastest -> each XCD
    // works a contiguous vertical strip; input slice fits its L2.
    const int bid = blockIdx.x;
    const int swz = (bid & 7) * (NBLK / 8) + (bid >> 3);
    const int b   = swz / (NTX * NTY);
    const int rr  = swz - b * (NTX * NTY);
    const int tx  = rr / NTY;
    const int ty  = rr - tx * NTY;
    const int x0  = tx * TW;
    const int y0  = ty * TH;

    const int tid  = threadIdx.x;
    const int wave = tid >> 6;
    const float* ibase = inp + (size_t)b * CC * HW;

    // ---- Stage input tile into LDS ----
    if (tx > 0 && tx < NTX - 1) {
        // Interior in x: async DMA straight to LDS. Dest = wave-uniform base +
        // lane*16B (linear chunk order); per-lane SOURCE encodes the layout.
        // All 5 rounds are full-exec (1280 chunk slots allocated); slots past
        // 1219 and pad slots load a duplicated valid address, never read.
#pragma unroll
        for (int e = 0; e < 5; ++e) {
            const int u = e * 256 + tid;
            const int q = u / CHUNKS_PER_ROW;
            const int r = u - q * CHUNKS_PER_ROW;
            const int s = min(q, ROWS - 1);
            int ch, t4;
            if (r < 60) { ch = r / 20; t4 = r - ch * 20; }
            else        { ch = 2;      t4 = 19; }   // pad slot: dup source
            const int grow = min(max(y0 - 5 + s, 0), HH - 1);
            const float* src = ibase + (size_t)ch * HW +
                               (size_t)grow * WW + (x0 - 8 + t4 * 4);
            lu32* dst = (lu32*)(void*)&lds[(e * 256 + wave * 64) * 4];
            __builtin_amdgcn_global_load_lds((gu32*)(const void*)src,
                                             dst, 16, 0, 0);
        }
    } else {
        // x-edge tile: scalar loads with per-column clamp into padded layout.
#pragma unroll
        for (int e = 0; e < 19; ++e) {
            const int idx = e * 256 + tid;          // 20*240 = 4800 total
            if (idx < ROWS * DATA_FLOATS_PER_ROW) {
                const int s   = idx / DATA_FLOATS_PER_ROW;
                const int rr2 = idx - s * DATA_FLOATS_PER_ROW;
                const int ch  = rr2 / COLS;
                const int t   = rr2 - ch * COLS;
                const int grow = min(max(y0 - 5 + s, 0), HH - 1);
                const int gcol = min(max(x0 - 8 + t, 0), WW - 1);
                lds[s * RSTRIDE + rr2] =
                    ibase[(size_t)ch * HW + (size_t)grow * WW + gcol];
            }
        }
    }

    // ---- Hoist flow + filter loads (both pixels) across the barrier ----
    const int lx = tid & (TW - 1);
    const int wy = tid >> 6;
    const int xA = x0 + lx;
    const int yA = y0 + wy;          // rows y0..y0+3
    const int remA = yA * WW + xA;
    const int remB = remA + 4 * WW;  // rows y0+4..y0+7

    const float fxA = flow[(size_t)(b * 2 + 0) * HW + remA];
    const float fyA = flow[(size_t)(b * 2 + 1) * HW + remA];
    const float fxB = flow[(size_t)(b * 2 + 0) * HW + remB];
    const float fyB = flow[(size_t)(b * 2 + 1) * HW + remB];

    float fA[16], fB[16];
    {
        const float* fpA = filt + (size_t)b * 16 * HW + remA;
#pragma unroll
        for (int k = 0; k < 16; ++k) fA[k] = fpA[(size_t)k * HW];
        const float* fpB = fpA + 4 * WW;
#pragma unroll
        for (int k = 0; k < 16; ++k) fB[k] = fpB[(size_t)k * HW];
    }

    __syncthreads();   // vmcnt(0) here also drains the global_load_lds DMA

    float accA[3], accB[3];
    compute_pixel(lds, ibase, xA, yA, x0, y0, fxA, fyA, fA, accA);
    compute_pixel(lds, ibase, xA, yA + 4, x0, y0, fxB, fyB, fB, accB);

    const int obA = b * CC * HW + remA;
    out[obA]          = accA[0];
    out[obA + HW]     = accA[1];
    out[obA + 2 * HW] = accA[2];
    const int obB = obA + 4 * WW;
    out[obB]          = accB[0];
    out[obB + HW]     = accB[1];
    out[obB + 2 * HW] = accB[2];
}

extern "C" void kernel_launch(void* const* d_in, const int* in_sizes, int n_in,
                              void* d_out, int out_size, void* d_ws, size_t ws_size,
                              hipStream_t stream) {
    const float* teninput  = (const float*)d_in[0];
    const float* tenflow   = (const float*)d_in[1];
    const float* tenfilter = (const float*)d_in[2];
    float* out = (float*)d_out;

    filter_interp_kernel<<<NBLK, 256, 0, stream>>>(teninput, tenflow, tenfilter, out);
}